// Round 11
// baseline (565.708 us; speedup 1.0000x reference)
//
#include <hip/hip_runtime.h>
#include <math.h>

#define BB 32
#define NNODE 1024
#define BN 32768
#define NE 262144
#define DD 128
#define NT 8
#define NSTEPS 6
#define NBIN 16                      // (dst-half)*8 + etype (bins kept; sq is global)
#define SORT_CAP (NE + 2048)         // bins padded to 128-edge tiles
#define NTILES_F 2064                // >= total padded tiles (2048 + 16)
#define M_CAP (NE + 2048)            // rows in message buffer (full E)

typedef __attribute__((ext_vector_type(8))) short bf16x8;
typedef __attribute__((ext_vector_type(4))) float f32x4;

static __device__ __forceinline__ float4 ld4(const float* p) { return *(const float4*)p; }
static __device__ __forceinline__ float sigmoidf_(float x) { return 1.f / (1.f + expf(-x)); }
// f32 -> bf16 round-to-nearest-even
static __device__ __forceinline__ unsigned f2b(float f) {
    unsigned u = __float_as_uint(f);
    return (u + 0x7FFFu + ((u >> 16) & 1u)) >> 16;
}
static __device__ __forceinline__ float b2f(unsigned short b) {
    return __uint_as_float(((unsigned)b) << 16);
}
static __device__ __forceinline__ unsigned pk(float a, float b) {
    return f2b(a) | (f2b(b) << 16);
}
// elementwise u16 max of packed pairs (valid ordering for non-negative bf16)
static __device__ __forceinline__ unsigned bmax2(unsigned a, unsigned b) {
    unsigned ah = a & 0xFFFF0000u, bh = b & 0xFFFF0000u;
    unsigned al = a & 0x0000FFFFu, bl = b & 0x0000FFFFu;
    return (ah > bh ? ah : bh) | (al > bl ? al : bl);
}
static __device__ __forceinline__ uint4 bmax4(uint4 a, uint4 b) {
    return make_uint4(bmax2(a.x, b.x), bmax2(a.y, b.y), bmax2(a.z, b.z), bmax2(a.w, b.w));
}
// unpack-accumulate: ac[0..15] += bf16 pairs of (w0,w1)
static __device__ __forceinline__ void upacc(float* ac, uint4 w0, uint4 w1) {
    ac[0] += b2f((unsigned short)(w0.x & 0xFFFF)); ac[1] += b2f((unsigned short)(w0.x >> 16));
    ac[2] += b2f((unsigned short)(w0.y & 0xFFFF)); ac[3] += b2f((unsigned short)(w0.y >> 16));
    ac[4] += b2f((unsigned short)(w0.z & 0xFFFF)); ac[5] += b2f((unsigned short)(w0.z >> 16));
    ac[6] += b2f((unsigned short)(w0.w & 0xFFFF)); ac[7] += b2f((unsigned short)(w0.w >> 16));
    ac[8] += b2f((unsigned short)(w1.x & 0xFFFF)); ac[9] += b2f((unsigned short)(w1.x >> 16));
    ac[10] += b2f((unsigned short)(w1.y & 0xFFFF)); ac[11] += b2f((unsigned short)(w1.y >> 16));
    ac[12] += b2f((unsigned short)(w1.z & 0xFFFF)); ac[13] += b2f((unsigned short)(w1.z >> 16));
    ac[14] += b2f((unsigned short)(w1.w & 0xFFFF)); ac[15] += b2f((unsigned short)(w1.w >> 16));
}

// ---------------- workspace layout (bytes) ----------------
static constexpr size_t OFF_HCUR = 0;                                   // BN*DD f32
static constexpr size_t OFF_HBF  = OFF_HCUR + (size_t)BN * DD * 4;      // BN*DD bf16
static constexpr size_t OFF_CNT  = OFF_HBF  + (size_t)BN * DD * 2;      // BN*NT i32
static constexpr size_t OFF_DOFF = OFF_CNT  + (size_t)BN * NT * 4;      // BN i32
static constexpr size_t OFF_DBLK = OFF_DOFF + (size_t)BN * 4;           // 512 B
static constexpr size_t OFF_HB   = OFF_DBLK + 512;                      // 256 B
static constexpr size_t OFF_SSRC = OFF_HB   + 256;                      // SORT_CAP i32
static constexpr size_t OFF_SDST = OFF_SSRC + (size_t)SORT_CAP * 4;
static constexpr size_t OFF_SQ   = OFF_SDST + (size_t)SORT_CAP * 4;
static constexpr size_t OFF_DCUR = OFF_SQ   + (size_t)SORT_CAP * 4;     // BN i32
static constexpr size_t OFF_DEG  = OFF_DCUR + (size_t)BN * 4;           // BN i32
static constexpr size_t OFF_WMB  = OFF_DEG  + (size_t)BN * 4;           // 8*128*128 bf16
static constexpr size_t OFF_WIHB = OFF_WMB  + (size_t)NT * DD * DD * 2;
static constexpr size_t OFF_WHHB = OFF_WIHB + (size_t)3 * DD * DD * 2;
static constexpr size_t OFF_W1PY = OFF_WHHB + (size_t)3 * DD * DD * 2;  // 3*128*128 bf16
static constexpr size_t OFF_W1PZ = OFF_W1PY + (size_t)3 * 128 * 128 * 2;// 3*256*256 bf16
static constexpr size_t OFF_W2YB = OFF_W1PZ + (size_t)3 * 256 * 256 * 2;// 128*128 bf16
static constexpr size_t OFF_W2ZB = OFF_W2YB + (size_t)128 * 128 * 2;    // 256*256 bf16
static constexpr size_t OFF_ABF  = OFF_W2ZB + (size_t)256 * 256 * 2;    // (unused now)
static constexpr size_t OFF_H0BF = OFF_ABF  + (size_t)BN * DD * 2;      // BN*DD bf16
static constexpr size_t OFF_UN   = OFF_H0BF + (size_t)BN * DD * 2;      // union region
// GGNN phase:   m[M_CAP][128] bf16 (67.6 MB)
static constexpr size_t OFF_M    = OFF_UN;
// conv phase (after GGNN; aliases m):
static constexpr size_t OFF_U1Y  = OFF_UN;                                 // 32*1024*128 bf16
static constexpr size_t OFF_U1Z  = OFF_U1Y + (size_t)32 * 1024 * 128 * 2;  // 32*1024*256 bf16
static constexpr size_t OFF_QY   = OFF_U1Z + (size_t)32 * 1024 * 256 * 2;  // 32*255*128 f32
static constexpr size_t OFF_QZ   = OFF_QY  + (size_t)32 * 255 * 128 * 4;   // 32*255*256 f32
static constexpr size_t CONV_SZ  = (size_t)32 * 1024 * 128 * 2 + (size_t)32 * 1024 * 256 * 2
                                 + (size_t)32 * 255 * 128 * 4 + (size_t)32 * 255 * 256 * 4;
static constexpr size_t M_SZ     = (size_t)M_CAP * 128 * 2;
static constexpr size_t UN_SZ    = (M_SZ > CONV_SZ ? M_SZ : CONV_SZ);
static constexpr size_t WS_NEED  = OFF_UN + UN_SZ;                         // ~117 MiB (ws = 256 MiB per fill evidence)

// ---------------- mega prep kernel: copies/converts/zeros everything ----------------
#define PREP_BLOCKS 6133
__global__ void k_prep(const float* __restrict__ h_in, float* __restrict__ hcur,
                       unsigned short* __restrict__ hbf, unsigned short* __restrict__ h0bf,
                       const float* __restrict__ Wmsg, unsigned short* __restrict__ wmb,
                       const float* __restrict__ wih, unsigned short* __restrict__ wihb,
                       const float* __restrict__ whh, unsigned short* __restrict__ whhb,
                       const float* __restrict__ c2w, unsigned short* __restrict__ w2yb,
                       const float* __restrict__ z2w, unsigned short* __restrict__ w2zb,
                       const float* __restrict__ c1w, unsigned short* __restrict__ w1py,
                       const float* __restrict__ z1w, unsigned short* __restrict__ w1pz,
                       int* __restrict__ cnt, int* __restrict__ hb,
                       int* __restrict__ ssrc, int* __restrict__ sdst)
{
    int blk = blockIdx.x, tid = threadIdx.x;
    if (blk < 4096) {
        int i = blk * 256 + tid;
        float4 v = ((const float4*)h_in)[i];
        ((float4*)hcur)[i] = v;
        uint2 p = make_uint2(pk(v.x, v.y), pk(v.z, v.w));
        ((uint2*)hbf)[i] = p;
        ((uint2*)h0bf)[i] = p;
    } else if (blk < 4224) {
        int i = (blk - 4096) * 256 + tid;
        float4 v = ((const float4*)Wmsg)[i];
        ((uint2*)wmb)[i] = make_uint2(pk(v.x, v.y), pk(v.z, v.w));
    } else if (blk < 4272) {
        int i = (blk - 4224) * 256 + tid;
        float4 v = ((const float4*)wih)[i];
        ((uint2*)wihb)[i] = make_uint2(pk(v.x, v.y), pk(v.z, v.w));
    } else if (blk < 4320) {
        int i = (blk - 4272) * 256 + tid;
        float4 v = ((const float4*)whh)[i];
        ((uint2*)whhb)[i] = make_uint2(pk(v.x, v.y), pk(v.z, v.w));
    } else if (blk < 4336) {
        int i = (blk - 4320) * 256 + tid;
        float4 v = ((const float4*)c2w)[i];
        ((uint2*)w2yb)[i] = make_uint2(pk(v.x, v.y), pk(v.z, v.w));
    } else if (blk < 4400) {
        int i = (blk - 4336) * 256 + tid;
        float4 v = ((const float4*)z2w)[i];
        ((uint2*)w2zb)[i] = make_uint2(pk(v.x, v.y), pk(v.z, v.w));
    } else if (blk < 4592) {
        int g = (blk - 4400) * 256 + tid;          // < 3*128*128
        int k = g >> 14, rem = g & 16383;
        w1py[g] = (unsigned short)f2b(c1w[(size_t)rem * 3 + k]);
    } else if (blk < 5360) {
        int g = (blk - 4592) * 256 + tid;          // < 3*256*256
        int k = g >> 16, rem = g & 65535;
        w1pz[g] = (unsigned short)f2b(z1w[(size_t)rem * 3 + k]);
    } else if (blk < 5616) {
        ((uint4*)cnt)[(blk - 5360) * 256 + tid] = make_uint4(0, 0, 0, 0);
    } else if (blk < 5617) {
        if (tid < 64) hb[tid] = 0;
    } else if (blk < 5875) {
        ((uint4*)ssrc)[(blk - 5617) * 256 + tid] = make_uint4(0, 0, 0, 0);
    } else {
        ((uint4*)sdst)[(blk - 5875) * 256 + tid] = make_uint4(~0u, ~0u, ~0u, ~0u);
    }
}

// ---------------- graph preprocessing ----------------
// hb layout: [0..15] hist, [16..32] aoff (17 entries), [33..48] cur

__global__ void k_hist(const int* __restrict__ et, const int* __restrict__ dst,
                       int* __restrict__ hb, int* __restrict__ cnt)
{
    __shared__ int lh[NBIN];
    int tid = threadIdx.x;
    if (tid < NBIN) lh[tid] = 0;
    __syncthreads();
    int base = blockIdx.x * 1024;
    for (int k = 0; k < 4; ++k) {
        int e = base + tid + k * 256;
        int t = et[e], d = dst[e];
        atomicAdd(&lh[((d >> 14) << 3) | t], 1);
        atomicAdd(&cnt[d * NT + t], 1);
    }
    __syncthreads();
    if (tid < NBIN) atomicAdd(&hb[tid], lh[tid]);
}

// per-node degree + block-local exclusive scan; dblk[blk] = block total
__global__ void k_degA(const int* __restrict__ cnt, int* __restrict__ deg,
                       int* __restrict__ doff, int* __restrict__ dblk)
{
    __shared__ int ps[256];
    int tid = threadIdx.x;
    int v = blockIdx.x * 256 + tid;
    const int* cv = cnt + (size_t)v * NT;
    int d = 0;
#pragma unroll
    for (int t = 0; t < NT; ++t) d += cv[t];
    deg[v] = d;
    ps[tid] = d;
    __syncthreads();
    for (int off = 1; off < 256; off <<= 1) {
        int x = 0;
        if (tid >= off) x = ps[tid - off];
        __syncthreads();
        ps[tid] += x;
        __syncthreads();
    }
    doff[v] = ps[tid] - d;
    if (tid == 255) dblk[blockIdx.x] = ps[255];
}

// 1 small block: bin-offset scan (16 bins) + global block-base scan (128 blocks)
__global__ void k_scan2(int* __restrict__ hb, int* __restrict__ dblk)
{
    __shared__ int s[128];
    int tid = threadIdx.x;            // 128 threads
    s[tid] = dblk[tid];
    __syncthreads();
    if (tid == 0) {
        int acc = 0;
        for (int t = 0; t < NBIN; ++t) {
            hb[16 + t] = acc;
            hb[33 + t] = acc;
            acc += ((hb[t] + 127) >> 7) << 7;
        }
        hb[32] = acc;
        int run = 0;
        for (int i = 0; i < 128; ++i) {
            int x = s[i]; s[i] = run; run += x;
        }
    }
    __syncthreads();
    dblk[tid] = s[tid];
}

__global__ void k_degB(int* __restrict__ doff, int* __restrict__ dcur,
                       const int* __restrict__ dblk)
{
    int v = blockIdx.x * 256 + threadIdx.x;
    int o = doff[v] + dblk[blockIdx.x];
    doff[v] = o;
    dcur[v] = o;
}

__global__ void k_scatter(const int* __restrict__ src, const int* __restrict__ dst,
                          const int* __restrict__ et, int* __restrict__ hb,
                          int* __restrict__ dcur,
                          int* __restrict__ ssrc, int* __restrict__ sdst, int* __restrict__ sq)
{
    __shared__ int lc[NBIN], lbase[NBIN];
    int tid = threadIdx.x;
    if (tid < NBIN) lc[tid] = 0;
    __syncthreads();
    int base = blockIdx.x * 1024;
    int myk[4], myr[4];
    for (int k = 0; k < 4; ++k) {
        int e = base + tid * 4 + k;
        int kk = ((dst[e] >> 14) << 3) | et[e];
        myk[k] = kk;
        myr[k] = atomicAdd(&lc[kk], 1);
    }
    __syncthreads();
    if (tid < NBIN) lbase[tid] = atomicAdd(&hb[33 + tid], lc[tid]);
    __syncthreads();
    for (int k = 0; k < 4; ++k) {
        int e = base + tid * 4 + k;
        int p = lbase[myk[k]] + myr[k];
        int d = dst[e];
        ssrc[p] = src[e];
        sdst[p] = d;
        sq[p] = atomicAdd(&dcur[d], 1);       // global dst-sorted position
    }
}

// ---------------- MFMA message pass: 128 same-etype edges -> m rows (no atomics) ----------------
// K-chunked [128][64] staging, 4 blocks/CU; pack epilogue splits cols across As/Ws.

__launch_bounds__(256, 4)
__global__ void k_msg(const int* __restrict__ ssrc, const int* __restrict__ sdst,
                      const int* __restrict__ sq, const int* __restrict__ hb,
                      const unsigned short* __restrict__ hbf,
                      const unsigned short* __restrict__ wmb,
                      unsigned short* __restrict__ m)
{
    __shared__ __align__(16) unsigned short As[128 * 64];
    __shared__ __align__(16) unsigned short Ws[128 * 64];
    __shared__ int sdl[128], ssl[128], sql[128];
    int base = blockIdx.x * 128;
    if (base >= hb[32]) return;               // uniform
    int bin = 0;
#pragma unroll
    for (int i = 1; i < NBIN; ++i) if (base >= hb[16 + i]) bin = i;
    int t = bin & 7;
    int tid = threadIdx.x;
    if (tid < 128) { sdl[tid] = sdst[base + tid]; ssl[tid] = ssrc[base + tid]; sql[tid] = sq[base + tid]; }
    __syncthreads();
    int lane = tid & 63, wvv = tid >> 6;
    int wm = (wvv >> 1) * 64, wn = (wvv & 1) * 64;
    int lr = lane & 15, lk = lane >> 4;
    f32x4 acc[4][4];
#pragma unroll
    for (int i = 0; i < 4; ++i)
#pragma unroll
        for (int j = 0; j < 4; ++j) acc[i][j] = (f32x4){0.f, 0.f, 0.f, 0.f};

    int r = tid >> 1, halfc = tid & 1;
    unsigned boff = r * 128 + halfc * 64;     // bytes, 128B rows
    unsigned sw = (r & 7) << 4;
    for (int c0 = 0; c0 < DD; c0 += 64) {
        if (c0) __syncthreads();              // WAR before restage
        {
            const uint4* hp = (const uint4*)(hbf + (size_t)ssl[r] * DD + c0 + halfc * 32);
            const uint4* wp = (const uint4*)(wmb + (size_t)t * DD * DD + (size_t)r * DD + c0 + halfc * 32);
#pragma unroll
            for (int c = 0; c < 4; ++c) {
                unsigned byte = (boff + c * 16) ^ sw;
                *(uint4*)((char*)As + byte) = hp[c];
                *(uint4*)((char*)Ws + byte) = wp[c];
            }
        }
        __syncthreads();
#pragma unroll
        for (int kc = 0; kc < 2; ++kc) {
            int cb = kc * 64 + lk * 16;
            bf16x8 af[4], bfv[4];
#pragma unroll
            for (int mi = 0; mi < 4; ++mi) {
                int row = wm + mi * 16 + lr;
                af[mi] = *(const bf16x8*)((const char*)As + ((row * 128 + cb) ^ ((row & 7) << 4)));
            }
#pragma unroll
            for (int ni = 0; ni < 4; ++ni) {
                int row = wn + ni * 16 + lr;
                bfv[ni] = *(const bf16x8*)((const char*)Ws + ((row * 128 + cb) ^ ((row & 7) << 4)));
            }
#pragma unroll
            for (int mi = 0; mi < 4; ++mi)
#pragma unroll
                for (int ni = 0; ni < 4; ++ni)
                    acc[mi][ni] = __builtin_amdgcn_mfma_f32_16x16x32_bf16(af[mi], bfv[ni], acc[mi][ni], 0, 0, 0);
        }
    }
    // pack epilogue: cols 0-63 -> As, 64-127 -> Ws (wave-disjoint by wn)
    __syncthreads();
    {
        unsigned short* tgt = wn ? Ws : As;
#pragma unroll
        for (int mi = 0; mi < 4; ++mi)
#pragma unroll
            for (int ni = 0; ni < 4; ++ni)
#pragma unroll
                for (int rg = 0; rg < 4; ++rg) {
                    int er = wm + mi * 16 + lk * 4 + rg;
                    int col = (wn + ni * 16 + lr) & 63;
                    unsigned byte = ((unsigned)(er * 128 + col * 2)) ^ ((er & 7) << 4);
                    *(unsigned short*)((char*)tgt + byte) = (unsigned short)f2b(acc[mi][ni][rg]);
                }
    }
    __syncthreads();
    int orow = tid >> 4, ochunk = tid & 15;
#pragma unroll
    for (int p = 0; p < 8; ++p) {
        int row = p * 16 + orow;
        if (sdl[row] >= 0) {
            const char* srcb = (ochunk < 8) ? (const char*)As : (const char*)Ws;
            unsigned byte = ((unsigned)(row * 128 + (ochunk & 7) * 16)) ^ ((row & 7) << 4);
            uint4 v = *(const uint4*)(srcb + byte);
            *(uint4*)(m + (size_t)sql[row] * 128 + ochunk * 8) = v;
        }
    }
}

// ---------------- merged GRU + aggregate: X = bias_seed + segment-sum(m) gathered in staging ----------------
// M=128 tile, 512 threads. Gather phase: each thread sums its 32-col slice over deg[v] m-rows
// (f32) + bias seed, packs bf16 into Xs. Then standard 6-phase MFMA GRU. Bit-identical to
// the previous k_agg+k_gru pair (same accumulate order, same rounding points).

__launch_bounds__(512, 2)
__global__ void k_gruagg(const unsigned short* __restrict__ m, const int* __restrict__ deg,
                         const int* __restrict__ doff, const int* __restrict__ cnt,
                         const float* __restrict__ bmsg,
                         float* __restrict__ h, unsigned short* __restrict__ hbf,
                         const unsigned short* __restrict__ wihb, const unsigned short* __restrict__ whhb,
                         const float* __restrict__ bih, const float* __restrict__ bhh)
{
    __shared__ __align__(16) unsigned short Xs[128 * 128];
    __shared__ __align__(16) unsigned short Ws2[128 * 128];
    __shared__ float bmS[NT * DD];
    int m0 = blockIdx.x * 128;
    int tid = threadIdx.x;
    // stage bias matrix (1024 f32) : 512 threads x 2
    ((float2*)bmS)[tid] = ((const float2*)bmsg)[tid];

    int rx = tid >> 2, qx = tid & 3;         // 128 rows x 4 quads of 32 cols
    unsigned bx = rx * 256 + qx * 64, swx = (rx & 7) << 4;
    int v = m0 + rx;
    int d = deg[v], off = doff[v];
    int cv[NT];
    {
        uint4 c0 = *(const uint4*)(cnt + (size_t)v * NT);
        uint4 c1 = *(const uint4*)(cnt + (size_t)v * NT + 4);
        cv[0] = c0.x; cv[1] = c0.y; cv[2] = c0.z; cv[3] = c0.w;
        cv[4] = c1.x; cv[5] = c1.y; cv[6] = c1.z; cv[7] = c1.w;
    }
    __syncthreads();                          // bmS visible
    // gather: X[v][qx*32 .. +32] = bias_seed + sum of message rows
#pragma unroll
    for (int half = 0; half < 2; ++half) {
        float ac[16];
#pragma unroll
        for (int j = 0; j < 16; ++j) ac[j] = 0.f;
#pragma unroll
        for (int t = 0; t < NT; ++t) {
            float c = (float)cv[t];
            const float* bp = &bmS[t * DD + qx * 32 + half * 16];
#pragma unroll
            for (int j = 0; j < 16; ++j) ac[j] += c * bp[j];
        }
        for (int e = 0; e < d; ++e) {
            const uint4* pp = (const uint4*)(m + ((size_t)(off + e)) * DD + qx * 32 + half * 16);
            upacc(ac, pp[0], pp[1]);
        }
        uint4 o0 = make_uint4(pk(ac[0], ac[1]), pk(ac[2], ac[3]), pk(ac[4], ac[5]), pk(ac[6], ac[7]));
        uint4 o1 = make_uint4(pk(ac[8], ac[9]), pk(ac[10], ac[11]), pk(ac[12], ac[13]), pk(ac[14], ac[15]));
        *(uint4*)((char*)Xs + ((bx + half * 32) ^ swx)) = o0;
        *(uint4*)((char*)Xs + ((bx + half * 32 + 16) ^ swx)) = o1;
    }

    int lane = tid & 63, wv = tid >> 6;      // 8 waves
    int wm = (wv >> 1) * 32, wn = (wv & 1) * 64;
    int lr = lane & 15, lk = lane >> 4;
    f32x4 aR[2][4], aZ[2][4], aI[2][4], aH[2][4];
#pragma unroll
    for (int i = 0; i < 2; ++i)
#pragma unroll
        for (int j = 0; j < 4; ++j) {
            aR[i][j] = (f32x4){0.f, 0.f, 0.f, 0.f};
            aZ[i][j] = (f32x4){0.f, 0.f, 0.f, 0.f};
            aI[i][j] = (f32x4){0.f, 0.f, 0.f, 0.f};
            aH[i][j] = (f32x4){0.f, 0.f, 0.f, 0.f};
        }
#pragma unroll
    for (int pass = 0; pass < 2; ++pass) {
        const unsigned short* W = pass ? whhb : wihb;
#pragma unroll
        for (int g = 0; g < 3; ++g) {
            __syncthreads();                 // WAR: prior reads of Xs/Ws2 done (first: gather visible)
            if (g == 0 && pass == 1) {       // pass 0 g 0: Xs already holds gathered X
                const uint4* sp = (const uint4*)(hbf + (size_t)(m0 + rx) * DD + qx * 32);
#pragma unroll
                for (int c = 0; c < 4; ++c)
                    *(uint4*)((char*)Xs + ((bx + c * 16) ^ swx)) = sp[c];
            }
            {
                const uint4* wp = (const uint4*)(W + (size_t)(g * DD + rx) * DD + qx * 32);
#pragma unroll
                for (int c = 0; c < 4; ++c)
                    *(uint4*)((char*)Ws2 + ((bx + c * 16) ^ swx)) = wp[c];
            }
            __syncthreads();
#pragma unroll
            for (int kc = 0; kc < 4; ++kc) {
                int cb = kc * 64 + lk * 16;
                bf16x8 af[2], bfv[4];
#pragma unroll
                for (int mi = 0; mi < 2; ++mi) {
                    int row = wm + mi * 16 + lr;
                    af[mi] = *(const bf16x8*)((const char*)Xs + ((row * 256 + cb) ^ ((row & 7) << 4)));
                }
#pragma unroll
                for (int ni = 0; ni < 4; ++ni) {
                    int row = wn + ni * 16 + lr;
                    bfv[ni] = *(const bf16x8*)((const char*)Ws2 + ((row * 256 + cb) ^ ((row & 7) << 4)));
                }
#pragma unroll
                for (int mi = 0; mi < 2; ++mi)
#pragma unroll
                    for (int ni = 0; ni < 4; ++ni) {
                        if (g == 0)
                            aR[mi][ni] = __builtin_amdgcn_mfma_f32_16x16x32_bf16(af[mi], bfv[ni], aR[mi][ni], 0, 0, 0);
                        else if (g == 1)
                            aZ[mi][ni] = __builtin_amdgcn_mfma_f32_16x16x32_bf16(af[mi], bfv[ni], aZ[mi][ni], 0, 0, 0);
                        else if (pass == 0)
                            aI[mi][ni] = __builtin_amdgcn_mfma_f32_16x16x32_bf16(af[mi], bfv[ni], aI[mi][ni], 0, 0, 0);
                        else
                            aH[mi][ni] = __builtin_amdgcn_mfma_f32_16x16x32_bf16(af[mi], bfv[ni], aH[mi][ni], 0, 0, 0);
                    }
            }
        }
    }
    // epilogue: full GRU combine in-register
#pragma unroll
    for (int ni = 0; ni < 4; ++ni) {
        int col = wn + ni * 16 + lr;
        float br_ = bih[col] + bhh[col];
        float bz_ = bih[DD + col] + bhh[DD + col];
        float bin_ = bih[2 * DD + col], bhn_ = bhh[2 * DD + col];
#pragma unroll
        for (int mi = 0; mi < 2; ++mi)
#pragma unroll
            for (int rg = 0; rg < 4; ++rg) {
                int vv = m0 + wm + mi * 16 + lk * 4 + rg;
                float rr = sigmoidf_(aR[mi][ni][rg] + br_);
                float zz = sigmoidf_(aZ[mi][ni][rg] + bz_);
                float nn = tanhf(aI[mi][ni][rg] + bin_ + rr * (aH[mi][ni][rg] + bhn_));
                float hold = h[(size_t)vv * DD + col];
                float hnew = (1.f - zz) * nn + zz * hold;
                h[(size_t)vv * DD + col] = hnew;
                hbf[(size_t)vv * DD + col] = (unsigned short)f2b(hnew);
            }
    }
}

// ---------------- MFMA conv1(k=3): U1[b][pos][co] = relu(conv+b), unpooled, bf16 ----------------

template <int CIN>
__launch_bounds__(256, 2)
__global__ void k_conv1m(const unsigned short* __restrict__ hbf, const unsigned short* __restrict__ h0bf,
                         const unsigned short* __restrict__ w1p, const float* __restrict__ bias,
                         unsigned short* __restrict__ U1)
{
    __shared__ __align__(16) unsigned short As[128 * 64];
    __shared__ __align__(16) unsigned short Ws[128 * 64];
    int p0 = blockIdx.x * 128, b = blockIdx.y, n0 = blockIdx.z * 128;
    int tid = threadIdx.x;
    int lane = tid & 63, wv = tid >> 6;
    int wm = (wv >> 1) * 64, wn = (wv & 1) * 64;
    int lr = lane & 15, lk = lane >> 4;
    f32x4 acc[4][4];
#pragma unroll
    for (int i = 0; i < 4; ++i)
#pragma unroll
        for (int j = 0; j < 4; ++j) acc[i][j] = (f32x4){0.f, 0.f, 0.f, 0.f};

    int r = tid >> 1, halfc = tid & 1;
    unsigned boff = r * 128 + halfc * 64;
    unsigned sw = (r & 7) << 4;
#pragma unroll
    for (int k = 0; k < 3; ++k) {
        for (int c0 = 0; c0 < CIN; c0 += 64) {
            __syncthreads();
            {
                int row = p0 + k + r; if (row > NNODE - 1) row = NNODE - 1;
                int ci = c0 + halfc * 32;
                const unsigned short* srcp = (CIN == 128 || ci < 128)
                    ? hbf  + ((size_t)(b * NNODE + row)) * DD + ci
                    : h0bf + ((size_t)(b * NNODE + row)) * DD + (ci - 128);
                const uint4* sp = (const uint4*)srcp;
#pragma unroll
                for (int c = 0; c < 4; ++c)
                    *(uint4*)((char*)As + ((boff + c * 16) ^ sw)) = sp[c];
            }
            {
                const uint4* wp = (const uint4*)(w1p + ((size_t)k * CIN + n0 + r) * CIN + c0 + halfc * 32);
#pragma unroll
                for (int c = 0; c < 4; ++c)
                    *(uint4*)((char*)Ws + ((boff + c * 16) ^ sw)) = wp[c];
            }
            __syncthreads();
#pragma unroll
            for (int kc = 0; kc < 2; ++kc) {
                int cb = kc * 64 + lk * 16;
                bf16x8 af[4], bfv[4];
#pragma unroll
                for (int mi = 0; mi < 4; ++mi) {
                    int row = wm + mi * 16 + lr;
                    af[mi] = *(const bf16x8*)((const char*)As + ((row * 128 + cb) ^ ((row & 7) << 4)));
                }
#pragma unroll
                for (int ni = 0; ni < 4; ++ni) {
                    int row = wn + ni * 16 + lr;
                    bfv[ni] = *(const bf16x8*)((const char*)Ws + ((row * 128 + cb) ^ ((row & 7) << 4)));
                }
#pragma unroll
                for (int mi = 0; mi < 4; ++mi)
#pragma unroll
                    for (int ni = 0; ni < 4; ++ni)
                        acc[mi][ni] = __builtin_amdgcn_mfma_f32_16x16x32_bf16(af[mi], bfv[ni], acc[mi][ni], 0, 0, 0);
            }
        }
    }
#pragma unroll
    for (int ni = 0; ni < 4; ++ni) {
        int co = n0 + wn + ni * 16 + lr;
        float bs = bias[co];
#pragma unroll
        for (int mi = 0; mi < 4; ++mi)
#pragma unroll
            for (int rg = 0; rg < 4; ++rg) {
                int pos = p0 + wm + mi * 16 + lk * 4 + rg;
                if (pos < NNODE - 2) {
                    float v = fmaxf(0.f, acc[mi][ni][rg] + bs);
                    U1[((size_t)b * NNODE + pos) * CIN + co] = (unsigned short)f2b(v);
                }
            }
    }
}

// ---------------- MFMA conv2(k=1): A = pool3(U1) on the fly; epilogue pool2 ----------------

template <int CIN>
__launch_bounds__(256, 2)
__global__ void k_conv2m(const unsigned short* __restrict__ U1, const unsigned short* __restrict__ w2b,
                         const float* __restrict__ bias, float* __restrict__ Q)
{
    __shared__ __align__(16) unsigned short As[128 * 64];
    __shared__ __align__(16) unsigned short Ws[128 * 64];
    int m0 = blockIdx.x * 128, b = blockIdx.y, n0 = blockIdx.z * 128;
    int tid = threadIdx.x;
    int lane = tid & 63, wv = tid >> 6;
    int wm = (wv >> 1) * 64, wn = (wv & 1) * 64;
    int lr = lane & 15, lk = lane >> 4;
    f32x4 acc[4][4];
#pragma unroll
    for (int i = 0; i < 4; ++i)
#pragma unroll
        for (int j = 0; j < 4; ++j) acc[i][j] = (f32x4){0.f, 0.f, 0.f, 0.f};

    int r = tid >> 1, halfc = tid & 1;
    unsigned boff = r * 128 + halfc * 64;
    unsigned sw = (r & 7) << 4;
    for (int c0 = 0; c0 < CIN; c0 += 64) {
        __syncthreads();
        {
            int pr = 2 * (m0 + r);
            int r0 = pr, r1 = pr + 1, r2v = pr + 2;
            if (r2v > NNODE - 1) r2v = NNODE - 1;
            if (r1 > NNODE - 1) r1 = NNODE - 1;
            int ci = c0 + halfc * 32;
            const unsigned short* bp = U1 + (size_t)b * NNODE * CIN + ci;
            const uint4* p0q = (const uint4*)(bp + (size_t)r0 * CIN);
            const uint4* p1q = (const uint4*)(bp + (size_t)r1 * CIN);
            const uint4* p2q = (const uint4*)(bp + (size_t)r2v * CIN);
#pragma unroll
            for (int c = 0; c < 4; ++c) {
                uint4 mm = bmax4(bmax4(p0q[c], p1q[c]), p2q[c]);
                *(uint4*)((char*)As + ((boff + c * 16) ^ sw)) = mm;
            }
        }
        {
            const uint4* wp = (const uint4*)(w2b + (size_t)(n0 + r) * CIN + c0 + halfc * 32);
#pragma unroll
            for (int c = 0; c < 4; ++c)
                *(uint4*)((char*)Ws + ((boff + c * 16) ^ sw)) = wp[c];
        }
        __syncthreads();
#pragma unroll
        for (int kc = 0; kc < 2; ++kc) {
            int cb = kc * 64 + lk * 16;
            bf16x8 af[4], bfv[4];
#pragma unroll
            for (int mi = 0; mi < 4; ++mi) {
                int row = wm + mi * 16 + lr;
                af[mi] = *(const bf16x8*)((const char*)As + ((row * 128 + cb) ^ ((row & 7) << 4)));
            }
#pragma unroll
            for (int ni = 0; ni < 4; ++ni) {
                int row = wn + ni * 16 + lr;
                bfv[ni] = *(const bf16x8*)((const char*)Ws + ((row * 128 + cb) ^ ((row & 7) << 4)));
            }
#pragma unroll
            for (int mi = 0; mi < 4; ++mi)
#pragma unroll
                for (int ni = 0; ni < 4; ++ni)
                    acc[mi][ni] = __builtin_amdgcn_mfma_f32_16x16x32_bf16(af[mi], bfv[ni], acc[mi][ni], 0, 0, 0);
        }
    }
#pragma unroll
    for (int ni = 0; ni < 4; ++ni) {
        int co = n0 + wn + ni * 16 + lr;
        float bs = bias[co];
#pragma unroll
        for (int mi = 0; mi < 4; ++mi) {
            int l0 = m0 + wm + mi * 16 + lk * 4;
            float v0 = fmaxf(0.f, acc[mi][ni][0] + bs);
            float v1 = fmaxf(0.f, acc[mi][ni][1] + bs);
            float v2 = fmaxf(0.f, acc[mi][ni][2] + bs);
            float v3 = fmaxf(0.f, acc[mi][ni][3] + bs);
            int jq = l0 >> 1;
            if (jq < 255)     Q[((size_t)b * 255 + jq) * CIN + co]     = fmaxf(v0, v1);
            if (jq + 1 < 255) Q[((size_t)b * 255 + jq + 1) * CIN + co] = fmaxf(v2, v3);
        }
    }
}

// ---------------- final reduction ----------------

__launch_bounds__(256)
__global__ void k_final(const float* __restrict__ QY, const float* __restrict__ QZ,
                        const float* __restrict__ wy, const float* __restrict__ by,
                        const float* __restrict__ wz, const float* __restrict__ bz,
                        float* __restrict__ out)
{
    int b = blockIdx.x, tid = threadIdx.x;
    float p = 0.f;
    if (tid < 255) {
        const float* qy = QY + ((size_t)(b * 255 + tid)) * 128;
        const float* qz = QZ + ((size_t)(b * 255 + tid)) * 256;
        float dy = 0.f, dz = 0.f;
        for (int c = 0; c < 128; c += 4) {
            float4 q = ld4(qy + c), wv = ld4(wy + c);
            dy += q.x * wv.x + q.y * wv.y + q.z * wv.z + q.w * wv.w;
        }
        for (int c = 0; c < 256; c += 4) {
            float4 q = ld4(qz + c), wv = ld4(wz + c);
            dz += q.x * wv.x + q.y * wv.y + q.z * wv.z + q.w * wv.w;
        }
        p = (dy + by[0]) * (dz + bz[0]);
    }
    __shared__ float red[4];
    for (int off = 32; off > 0; off >>= 1) p += __shfl_down(p, off);
    if ((tid & 63) == 0) red[tid >> 6] = p;
    __syncthreads();
    if (tid == 0) {
        float s = red[0] + red[1] + red[2] + red[3];
        out[b] = 1.f / (1.f + expf(-s / 255.f));
    }
}

// ---------------- launch ----------------

extern "C" void kernel_launch(void* const* d_in, const int* in_sizes, int n_in,
                              void* d_out, int out_size, void* d_ws, size_t ws_size,
                              hipStream_t stream)
{
    const float* h_in = (const float*)d_in[0];
    const int* src = (const int*)d_in[1];
    const int* dst = (const int*)d_in[2];
    const int* et  = (const int*)d_in[3];
    const float* Wmsg = (const float*)d_in[4];
    const float* bmsg = (const float*)d_in[5];
    const float* wih = (const float*)d_in[6];
    const float* whh = (const float*)d_in[7];
    const float* bih = (const float*)d_in[8];
    const float* bhh = (const float*)d_in[9];
    const float* c1w = (const float*)d_in[10];
    const float* c1b = (const float*)d_in[11];
    const float* c2w = (const float*)d_in[12];
    const float* c2b = (const float*)d_in[13];
    const float* z1w = (const float*)d_in[14];
    const float* z1b = (const float*)d_in[15];
    const float* z2w = (const float*)d_in[16];
    const float* z2b = (const float*)d_in[17];
    const float* wy  = (const float*)d_in[18];
    const float* by  = (const float*)d_in[19];
    const float* wz  = (const float*)d_in[20];
    const float* bz  = (const float*)d_in[21];
    float* out = (float*)d_out;

    if (ws_size < WS_NEED) return;   // loud failure: output stays poisoned

    char* ws = (char*)d_ws;
    float* hcur = (float*)(ws + OFF_HCUR);
    unsigned short* hbf  = (unsigned short*)(ws + OFF_HBF);
    int*   cnt  = (int*)(ws + OFF_CNT);
    int*   doff = (int*)(ws + OFF_DOFF);
    int*   dblk = (int*)(ws + OFF_DBLK);
    int*   hb   = (int*)(ws + OFF_HB);
    int*   ssrc = (int*)(ws + OFF_SSRC);
    int*   sdst = (int*)(ws + OFF_SDST);
    int*   sq   = (int*)(ws + OFF_SQ);
    int*   dcur = (int*)(ws + OFF_DCUR);
    int*   deg  = (int*)(ws + OFF_DEG);
    unsigned short* wmb  = (unsigned short*)(ws + OFF_WMB);
    unsigned short* wihb = (unsigned short*)(ws + OFF_WIHB);
    unsigned short* whhb = (unsigned short*)(ws + OFF_WHHB);
    unsigned short* w1py = (unsigned short*)(ws + OFF_W1PY);
    unsigned short* w1pz = (unsigned short*)(ws + OFF_W1PZ);
    unsigned short* w2yb = (unsigned short*)(ws + OFF_W2YB);
    unsigned short* w2zb = (unsigned short*)(ws + OFF_W2ZB);
    unsigned short* h0bf = (unsigned short*)(ws + OFF_H0BF);
    unsigned short* mbuf = (unsigned short*)(ws + OFF_M);
    unsigned short* U1Y  = (unsigned short*)(ws + OFF_U1Y);
    unsigned short* U1Z  = (unsigned short*)(ws + OFF_U1Z);
    float* QY   = (float*)(ws + OFF_QY);
    float* QZ   = (float*)(ws + OFF_QZ);

    k_prep<<<PREP_BLOCKS, 256, 0, stream>>>(h_in, hcur, hbf, h0bf, Wmsg, wmb, wih, wihb, whh, whhb,
                                            c2w, w2yb, z2w, w2zb, c1w, w1py, z1w, w1pz,
                                            cnt, hb, ssrc, sdst);

    k_hist<<<256, 256, 0, stream>>>(et, dst, hb, cnt);
    k_degA<<<128, 256, 0, stream>>>(cnt, deg, doff, dblk);
    k_scan2<<<1, 128, 0, stream>>>(hb, dblk);
    k_degB<<<128, 256, 0, stream>>>(doff, dcur, dblk);
    k_scatter<<<256, 256, 0, stream>>>(src, dst, et, hb, dcur, ssrc, sdst, sq);

    for (int s = 0; s < NSTEPS; ++s) {
        k_msg<<<NTILES_F, 256, 0, stream>>>(ssrc, sdst, sq, hb, hbf, wmb, mbuf);
        k_gruagg<<<BN / 128, 512, 0, stream>>>(mbuf, deg, doff, cnt, bmsg,
                                               hcur, hbf, wihb, whhb, bih, bhh);
    }

    k_conv1m<128><<<dim3(8, 32, 1), 256, 0, stream>>>(hbf, h0bf, w1py, c1b, U1Y);
    k_conv2m<128><<<dim3(4, 32, 1), 256, 0, stream>>>(U1Y, w2yb, c2b, QY);
    k_conv1m<256><<<dim3(8, 32, 2), 256, 0, stream>>>(hbf, h0bf, w1pz, z1b, U1Z);
    k_conv2m<256><<<dim3(4, 32, 2), 256, 0, stream>>>(U1Z, w2zb, z2b, QZ);
    k_final<<<32, 256, 0, stream>>>(QY, QZ, wy, by, wz, bz, out);
}

// Round 12
// 553.998 us; speedup vs baseline: 1.0211x; 1.0211x over previous
//
#include <hip/hip_runtime.h>
#include <math.h>

#define BB 32
#define NNODE 1024
#define BN 32768
#define NE 262144
#define DD 128
#define NT 8
#define NSTEPS 6
#define NBIN 16                      // (dst-half)*8 + etype (bins kept; sq is global)
#define SORT_CAP (NE + 2048)         // bins padded to 128-edge tiles
#define NTILES_F 2064                // >= total padded tiles (2048 + 16)
#define M_CAP (NE + 2048)            // rows in message buffer (full E)

typedef __attribute__((ext_vector_type(8))) short bf16x8;
typedef __attribute__((ext_vector_type(4))) float f32x4;

static __device__ __forceinline__ float4 ld4(const float* p) { return *(const float4*)p; }
static __device__ __forceinline__ float sigmoidf_(float x) { return 1.f / (1.f + expf(-x)); }
// f32 -> bf16 round-to-nearest-even
static __device__ __forceinline__ unsigned f2b(float f) {
    unsigned u = __float_as_uint(f);
    return (u + 0x7FFFu + ((u >> 16) & 1u)) >> 16;
}
static __device__ __forceinline__ float b2f(unsigned short b) {
    return __uint_as_float(((unsigned)b) << 16);
}
static __device__ __forceinline__ unsigned pk(float a, float b) {
    return f2b(a) | (f2b(b) << 16);
}
// elementwise u16 max of packed pairs (valid ordering for non-negative bf16)
static __device__ __forceinline__ unsigned bmax2(unsigned a, unsigned b) {
    unsigned ah = a & 0xFFFF0000u, bh = b & 0xFFFF0000u;
    unsigned al = a & 0x0000FFFFu, bl = b & 0x0000FFFFu;
    return (ah > bh ? ah : bh) | (al > bl ? al : bl);
}
static __device__ __forceinline__ uint4 bmax4(uint4 a, uint4 b) {
    return make_uint4(bmax2(a.x, b.x), bmax2(a.y, b.y), bmax2(a.z, b.z), bmax2(a.w, b.w));
}

// ---------------- workspace layout (bytes) ----------------
static constexpr size_t OFF_HCUR = 0;                                   // BN*DD f32
static constexpr size_t OFF_HBF  = OFF_HCUR + (size_t)BN * DD * 4;      // BN*DD bf16
static constexpr size_t OFF_CNT  = OFF_HBF  + (size_t)BN * DD * 2;      // BN*NT i32
static constexpr size_t OFF_DOFF = OFF_CNT  + (size_t)BN * NT * 4;      // BN i32
static constexpr size_t OFF_DBLK = OFF_DOFF + (size_t)BN * 4;           // 512 B
static constexpr size_t OFF_HB   = OFF_DBLK + 512;                      // 256 B
static constexpr size_t OFF_SSRC = OFF_HB   + 256;                      // SORT_CAP i32
static constexpr size_t OFF_SDST = OFF_SSRC + (size_t)SORT_CAP * 4;
static constexpr size_t OFF_SQ   = OFF_SDST + (size_t)SORT_CAP * 4;
static constexpr size_t OFF_DCUR = OFF_SQ   + (size_t)SORT_CAP * 4;     // BN i32
static constexpr size_t OFF_DEG  = OFF_DCUR + (size_t)BN * 4;           // BN i32
static constexpr size_t OFF_WMB  = OFF_DEG  + (size_t)BN * 4;           // 8*128*128 bf16
static constexpr size_t OFF_WIHB = OFF_WMB  + (size_t)NT * DD * DD * 2;
static constexpr size_t OFF_WHHB = OFF_WIHB + (size_t)3 * DD * DD * 2;
static constexpr size_t OFF_W1PY = OFF_WHHB + (size_t)3 * DD * DD * 2;  // 3*128*128 bf16
static constexpr size_t OFF_W1PZ = OFF_W1PY + (size_t)3 * 128 * 128 * 2;// 3*256*256 bf16
static constexpr size_t OFF_W2YB = OFF_W1PZ + (size_t)3 * 256 * 256 * 2;// 128*128 bf16
static constexpr size_t OFF_W2ZB = OFF_W2YB + (size_t)128 * 128 * 2;    // 256*256 bf16
static constexpr size_t OFF_ABF  = OFF_W2ZB + (size_t)256 * 256 * 2;    // BN*DD bf16
static constexpr size_t OFF_H0BF = OFF_ABF  + (size_t)BN * DD * 2;      // BN*DD bf16
static constexpr size_t OFF_UN   = OFF_H0BF + (size_t)BN * DD * 2;      // union region
// GGNN phase:   m[M_CAP][128] bf16 (67.6 MB)
static constexpr size_t OFF_M    = OFF_UN;
// conv phase (after GGNN; aliases m):
static constexpr size_t OFF_U1Y  = OFF_UN;                                 // 32*1024*128 bf16
static constexpr size_t OFF_U1Z  = OFF_U1Y + (size_t)32 * 1024 * 128 * 2;  // 32*1024*256 bf16
static constexpr size_t OFF_QY   = OFF_U1Z + (size_t)32 * 1024 * 256 * 2;  // 32*255*128 f32
static constexpr size_t OFF_QZ   = OFF_QY  + (size_t)32 * 255 * 128 * 4;   // 32*255*256 f32
static constexpr size_t CONV_SZ  = (size_t)32 * 1024 * 128 * 2 + (size_t)32 * 1024 * 256 * 2
                                 + (size_t)32 * 255 * 128 * 4 + (size_t)32 * 255 * 256 * 4;
static constexpr size_t M_SZ     = (size_t)M_CAP * 128 * 2;
static constexpr size_t UN_SZ    = (M_SZ > CONV_SZ ? M_SZ : CONV_SZ);
static constexpr size_t WS_NEED  = OFF_UN + UN_SZ;                         // ~117 MiB (ws = 256 MiB per fill evidence)

// ---------------- mega prep kernel: copies/converts/zeros everything ----------------
#define PREP_BLOCKS 6133
__global__ void k_prep(const float* __restrict__ h_in, float* __restrict__ hcur,
                       unsigned short* __restrict__ hbf, unsigned short* __restrict__ h0bf,
                       const float* __restrict__ Wmsg, unsigned short* __restrict__ wmb,
                       const float* __restrict__ wih, unsigned short* __restrict__ wihb,
                       const float* __restrict__ whh, unsigned short* __restrict__ whhb,
                       const float* __restrict__ c2w, unsigned short* __restrict__ w2yb,
                       const float* __restrict__ z2w, unsigned short* __restrict__ w2zb,
                       const float* __restrict__ c1w, unsigned short* __restrict__ w1py,
                       const float* __restrict__ z1w, unsigned short* __restrict__ w1pz,
                       int* __restrict__ cnt, int* __restrict__ hb,
                       int* __restrict__ ssrc, int* __restrict__ sdst)
{
    int blk = blockIdx.x, tid = threadIdx.x;
    if (blk < 4096) {
        int i = blk * 256 + tid;
        float4 v = ((const float4*)h_in)[i];
        ((float4*)hcur)[i] = v;
        uint2 p = make_uint2(pk(v.x, v.y), pk(v.z, v.w));
        ((uint2*)hbf)[i] = p;
        ((uint2*)h0bf)[i] = p;
    } else if (blk < 4224) {
        int i = (blk - 4096) * 256 + tid;
        float4 v = ((const float4*)Wmsg)[i];
        ((uint2*)wmb)[i] = make_uint2(pk(v.x, v.y), pk(v.z, v.w));
    } else if (blk < 4272) {
        int i = (blk - 4224) * 256 + tid;
        float4 v = ((const float4*)wih)[i];
        ((uint2*)wihb)[i] = make_uint2(pk(v.x, v.y), pk(v.z, v.w));
    } else if (blk < 4320) {
        int i = (blk - 4272) * 256 + tid;
        float4 v = ((const float4*)whh)[i];
        ((uint2*)whhb)[i] = make_uint2(pk(v.x, v.y), pk(v.z, v.w));
    } else if (blk < 4336) {
        int i = (blk - 4320) * 256 + tid;
        float4 v = ((const float4*)c2w)[i];
        ((uint2*)w2yb)[i] = make_uint2(pk(v.x, v.y), pk(v.z, v.w));
    } else if (blk < 4400) {
        int i = (blk - 4336) * 256 + tid;
        float4 v = ((const float4*)z2w)[i];
        ((uint2*)w2zb)[i] = make_uint2(pk(v.x, v.y), pk(v.z, v.w));
    } else if (blk < 4592) {
        int g = (blk - 4400) * 256 + tid;          // < 3*128*128
        int k = g >> 14, rem = g & 16383;
        w1py[g] = (unsigned short)f2b(c1w[(size_t)rem * 3 + k]);
    } else if (blk < 5360) {
        int g = (blk - 4592) * 256 + tid;          // < 3*256*256
        int k = g >> 16, rem = g & 65535;
        w1pz[g] = (unsigned short)f2b(z1w[(size_t)rem * 3 + k]);
    } else if (blk < 5616) {
        ((uint4*)cnt)[(blk - 5360) * 256 + tid] = make_uint4(0, 0, 0, 0);
    } else if (blk < 5617) {
        if (tid < 64) hb[tid] = 0;
    } else if (blk < 5875) {
        ((uint4*)ssrc)[(blk - 5617) * 256 + tid] = make_uint4(0, 0, 0, 0);
    } else {
        ((uint4*)sdst)[(blk - 5875) * 256 + tid] = make_uint4(~0u, ~0u, ~0u, ~0u);
    }
}

// ---------------- graph preprocessing ----------------
// hb layout: [0..15] hist, [16..32] aoff (17 entries), [33..48] cur

__global__ void k_hist(const int* __restrict__ et, const int* __restrict__ dst,
                       int* __restrict__ hb, int* __restrict__ cnt)
{
    __shared__ int lh[NBIN];
    int tid = threadIdx.x;
    if (tid < NBIN) lh[tid] = 0;
    __syncthreads();
    int base = blockIdx.x * 1024;
    for (int k = 0; k < 4; ++k) {
        int e = base + tid + k * 256;
        int t = et[e], d = dst[e];
        atomicAdd(&lh[((d >> 14) << 3) | t], 1);
        atomicAdd(&cnt[d * NT + t], 1);
    }
    __syncthreads();
    if (tid < NBIN) atomicAdd(&hb[tid], lh[tid]);
}

// per-node degree + block-local exclusive scan; dblk[blk] = block total
__global__ void k_degA(const int* __restrict__ cnt, int* __restrict__ deg,
                       int* __restrict__ doff, int* __restrict__ dblk)
{
    __shared__ int ps[256];
    int tid = threadIdx.x;
    int v = blockIdx.x * 256 + tid;
    const int* cv = cnt + (size_t)v * NT;
    int d = 0;
#pragma unroll
    for (int t = 0; t < NT; ++t) d += cv[t];
    deg[v] = d;
    ps[tid] = d;
    __syncthreads();
    for (int off = 1; off < 256; off <<= 1) {
        int x = 0;
        if (tid >= off) x = ps[tid - off];
        __syncthreads();
        ps[tid] += x;
        __syncthreads();
    }
    doff[v] = ps[tid] - d;
    if (tid == 255) dblk[blockIdx.x] = ps[255];
}

// 1 small block: bin-offset scan (16 bins) + global block-base scan (128 blocks)
__global__ void k_scan2(int* __restrict__ hb, int* __restrict__ dblk)
{
    __shared__ int s[128];
    int tid = threadIdx.x;            // 128 threads
    s[tid] = dblk[tid];
    __syncthreads();
    if (tid == 0) {
        int acc = 0;
        for (int t = 0; t < NBIN; ++t) {
            hb[16 + t] = acc;
            hb[33 + t] = acc;
            acc += ((hb[t] + 127) >> 7) << 7;
        }
        hb[32] = acc;
        int run = 0;
        for (int i = 0; i < 128; ++i) {
            int x = s[i]; s[i] = run; run += x;
        }
    }
    __syncthreads();
    dblk[tid] = s[tid];
}

__global__ void k_degB(int* __restrict__ doff, int* __restrict__ dcur,
                       const int* __restrict__ dblk)
{
    int v = blockIdx.x * 256 + threadIdx.x;
    int o = doff[v] + dblk[blockIdx.x];
    doff[v] = o;
    dcur[v] = o;
}

__global__ void k_scatter(const int* __restrict__ src, const int* __restrict__ dst,
                          const int* __restrict__ et, int* __restrict__ hb,
                          int* __restrict__ dcur,
                          int* __restrict__ ssrc, int* __restrict__ sdst, int* __restrict__ sq)
{
    __shared__ int lc[NBIN], lbase[NBIN];
    int tid = threadIdx.x;
    if (tid < NBIN) lc[tid] = 0;
    __syncthreads();
    int base = blockIdx.x * 1024;
    int myk[4], myr[4];
    for (int k = 0; k < 4; ++k) {
        int e = base + tid * 4 + k;
        int kk = ((dst[e] >> 14) << 3) | et[e];
        myk[k] = kk;
        myr[k] = atomicAdd(&lc[kk], 1);
    }
    __syncthreads();
    if (tid < NBIN) lbase[tid] = atomicAdd(&hb[33 + tid], lc[tid]);
    __syncthreads();
    for (int k = 0; k < 4; ++k) {
        int e = base + tid * 4 + k;
        int p = lbase[myk[k]] + myr[k];
        int d = dst[e];
        ssrc[p] = src[e];
        sdst[p] = d;
        sq[p] = atomicAdd(&dcur[d], 1);       // global dst-sorted position
    }
}

// ---------------- MFMA message pass: 128 same-etype edges -> m rows (no atomics) ----------------
// K-chunked [128][64] staging, 4 blocks/CU; pack epilogue splits cols across As/Ws.

__launch_bounds__(256, 4)
__global__ void k_msg(const int* __restrict__ ssrc, const int* __restrict__ sdst,
                      const int* __restrict__ sq, const int* __restrict__ hb,
                      const unsigned short* __restrict__ hbf,
                      const unsigned short* __restrict__ wmb,
                      unsigned short* __restrict__ m)
{
    __shared__ __align__(16) unsigned short As[128 * 64];
    __shared__ __align__(16) unsigned short Ws[128 * 64];
    __shared__ int sdl[128], ssl[128], sql[128];
    int base = blockIdx.x * 128;
    if (base >= hb[32]) return;               // uniform
    int bin = 0;
#pragma unroll
    for (int i = 1; i < NBIN; ++i) if (base >= hb[16 + i]) bin = i;
    int t = bin & 7;
    int tid = threadIdx.x;
    if (tid < 128) { sdl[tid] = sdst[base + tid]; ssl[tid] = ssrc[base + tid]; sql[tid] = sq[base + tid]; }
    __syncthreads();
    int lane = tid & 63, wvv = tid >> 6;
    int wm = (wvv >> 1) * 64, wn = (wvv & 1) * 64;
    int lr = lane & 15, lk = lane >> 4;
    f32x4 acc[4][4];
#pragma unroll
    for (int i = 0; i < 4; ++i)
#pragma unroll
        for (int j = 0; j < 4; ++j) acc[i][j] = (f32x4){0.f, 0.f, 0.f, 0.f};

    int r = tid >> 1, halfc = tid & 1;
    unsigned boff = r * 128 + halfc * 64;     // bytes, 128B rows
    unsigned sw = (r & 7) << 4;
    for (int c0 = 0; c0 < DD; c0 += 64) {
        if (c0) __syncthreads();              // WAR before restage
        {
            const uint4* hp = (const uint4*)(hbf + (size_t)ssl[r] * DD + c0 + halfc * 32);
            const uint4* wp = (const uint4*)(wmb + (size_t)t * DD * DD + (size_t)r * DD + c0 + halfc * 32);
#pragma unroll
            for (int c = 0; c < 4; ++c) {
                unsigned byte = (boff + c * 16) ^ sw;
                *(uint4*)((char*)As + byte) = hp[c];
                *(uint4*)((char*)Ws + byte) = wp[c];
            }
        }
        __syncthreads();
#pragma unroll
        for (int kc = 0; kc < 2; ++kc) {
            int cb = kc * 64 + lk * 16;
            bf16x8 af[4], bfv[4];
#pragma unroll
            for (int mi = 0; mi < 4; ++mi) {
                int row = wm + mi * 16 + lr;
                af[mi] = *(const bf16x8*)((const char*)As + ((row * 128 + cb) ^ ((row & 7) << 4)));
            }
#pragma unroll
            for (int ni = 0; ni < 4; ++ni) {
                int row = wn + ni * 16 + lr;
                bfv[ni] = *(const bf16x8*)((const char*)Ws + ((row * 128 + cb) ^ ((row & 7) << 4)));
            }
#pragma unroll
            for (int mi = 0; mi < 4; ++mi)
#pragma unroll
                for (int ni = 0; ni < 4; ++ni)
                    acc[mi][ni] = __builtin_amdgcn_mfma_f32_16x16x32_bf16(af[mi], bfv[ni], acc[mi][ni], 0, 0, 0);
        }
    }
    // pack epilogue: cols 0-63 -> As, 64-127 -> Ws (wave-disjoint by wn)
    __syncthreads();
    {
        unsigned short* tgt = wn ? Ws : As;
#pragma unroll
        for (int mi = 0; mi < 4; ++mi)
#pragma unroll
            for (int ni = 0; ni < 4; ++ni)
#pragma unroll
                for (int rg = 0; rg < 4; ++rg) {
                    int er = wm + mi * 16 + lk * 4 + rg;
                    int col = (wn + ni * 16 + lr) & 63;
                    unsigned byte = ((unsigned)(er * 128 + col * 2)) ^ ((er & 7) << 4);
                    *(unsigned short*)((char*)tgt + byte) = (unsigned short)f2b(acc[mi][ni][rg]);
                }
    }
    __syncthreads();
    int orow = tid >> 4, ochunk = tid & 15;
#pragma unroll
    for (int p = 0; p < 8; ++p) {
        int row = p * 16 + orow;
        if (sdl[row] >= 0) {
            const char* srcb = (ochunk < 8) ? (const char*)As : (const char*)Ws;
            unsigned byte = ((unsigned)(row * 128 + (ochunk & 7) * 16)) ^ ((row & 7) << 4);
            uint4 v = *(const uint4*)(srcb + byte);
            *(uint4*)(m + (size_t)sql[row] * 128 + ochunk * 8) = v;
        }
    }
}

// ---------------- segment-sum: abf[v] = bf16( bias_seed(v) + sum of its message rows ) ----------------
// lanes 0-31: even rows + bias; lanes 32-63: odd rows; shfl_xor(32) combine.

__launch_bounds__(256)
__global__ void k_agg(const unsigned short* __restrict__ m, const int* __restrict__ deg,
                      const int* __restrict__ doff, const int* __restrict__ cnt,
                      const float* __restrict__ bmsg, unsigned short* __restrict__ abf)
{
    __shared__ float bm[NT * DD];
    int tid = threadIdx.x;
    *(float4*)&bm[tid * 4] = ld4(bmsg + tid * 4);   // 256*4 = 1024 = 8*128
    __syncthreads();
    int wv = tid >> 6, lane = tid & 63;
    int v = blockIdx.x * 4 + wv;
    int lh = lane >> 5;          // 0: even rows (+bias), 1: odd rows
    int lc = lane & 31;          // cols [4*lc, 4*lc+4)
    float a0 = 0.f, a1 = 0.f, a2 = 0.f, a3 = 0.f;
    if (lh == 0) {
        const int* cv = cnt + (size_t)v * NT;
        int c0 = lc * 4;
#pragma unroll
        for (int t = 0; t < NT; ++t) {
            float c = (float)cv[t];
            a0 += c * bm[t * DD + c0];
            a1 += c * bm[t * DD + c0 + 1];
            a2 += c * bm[t * DD + c0 + 2];
            a3 += c * bm[t * DD + c0 + 3];
        }
    }
    int d = deg[v], off = doff[v];
    const uint2* mr = (const uint2*)m;   // 8B granules, 32 per row
    int npair = d >> 1;
    for (int i = 0; i < npair; ++i) {
        uint2 w = mr[(size_t)(off + 2 * i + lh) * 32 + lc];
        a0 += b2f((unsigned short)(w.x & 0xFFFF));
        a1 += b2f((unsigned short)(w.x >> 16));
        a2 += b2f((unsigned short)(w.y & 0xFFFF));
        a3 += b2f((unsigned short)(w.y >> 16));
    }
    if ((d & 1) && lh == 0) {
        uint2 w = mr[(size_t)(off + d - 1) * 32 + lc];
        a0 += b2f((unsigned short)(w.x & 0xFFFF));
        a1 += b2f((unsigned short)(w.x >> 16));
        a2 += b2f((unsigned short)(w.y & 0xFFFF));
        a3 += b2f((unsigned short)(w.y >> 16));
    }
    a0 += __shfl_xor(a0, 32);
    a1 += __shfl_xor(a1, 32);
    a2 += __shfl_xor(a2, 32);
    a3 += __shfl_xor(a3, 32);
    if (lh == 0)
        ((uint2*)abf)[(size_t)v * 32 + lc] = make_uint2(pk(a0, a1), pk(a2, a3));
}

// ---------------- merged MFMA GRU: M=128 tile, 512 threads, all gates in-register ----------------

__launch_bounds__(512, 2)
__global__ void k_gru(const unsigned short* __restrict__ abf, float* __restrict__ h,
                      unsigned short* __restrict__ hbf,
                      const unsigned short* __restrict__ wihb, const unsigned short* __restrict__ whhb,
                      const float* __restrict__ bih, const float* __restrict__ bhh)
{
    __shared__ __align__(16) unsigned short Xs[128 * 128];
    __shared__ __align__(16) unsigned short Ws2[128 * 128];
    int m0 = blockIdx.x * 128;
    int tid = threadIdx.x;
    int lane = tid & 63, wv = tid >> 6;      // 8 waves
    int wm = (wv >> 1) * 32, wn = (wv & 1) * 64;
    int lr = lane & 15, lk = lane >> 4;
    f32x4 aR[2][4], aZ[2][4], aI[2][4], aH[2][4];
#pragma unroll
    for (int i = 0; i < 2; ++i)
#pragma unroll
        for (int j = 0; j < 4; ++j) {
            aR[i][j] = (f32x4){0.f, 0.f, 0.f, 0.f};
            aZ[i][j] = (f32x4){0.f, 0.f, 0.f, 0.f};
            aI[i][j] = (f32x4){0.f, 0.f, 0.f, 0.f};
            aH[i][j] = (f32x4){0.f, 0.f, 0.f, 0.f};
        }
    int rx = tid >> 2, qx = tid & 3;         // 128 rows x 4 quads (512 threads)
    unsigned bx = rx * 256 + qx * 64, swx = (rx & 7) << 4;
#pragma unroll
    for (int pass = 0; pass < 2; ++pass) {
        const unsigned short* X = pass ? hbf : abf;
        const unsigned short* W = pass ? whhb : wihb;
#pragma unroll
        for (int g = 0; g < 3; ++g) {
            __syncthreads();                 // WAR: prior reads of Xs/Ws2 done
            if (g == 0) {
                const uint4* sp = (const uint4*)(X + (size_t)(m0 + rx) * DD + qx * 32);
#pragma unroll
                for (int c = 0; c < 4; ++c)
                    *(uint4*)((char*)Xs + ((bx + c * 16) ^ swx)) = sp[c];
            }
            {
                const uint4* wp = (const uint4*)(W + (size_t)(g * DD + rx) * DD + qx * 32);
#pragma unroll
                for (int c = 0; c < 4; ++c)
                    *(uint4*)((char*)Ws2 + ((bx + c * 16) ^ swx)) = wp[c];
            }
            __syncthreads();
#pragma unroll
            for (int kc = 0; kc < 4; ++kc) {
                int cb = kc * 64 + lk * 16;
                bf16x8 af[2], bfv[4];
#pragma unroll
                for (int mi = 0; mi < 2; ++mi) {
                    int row = wm + mi * 16 + lr;
                    af[mi] = *(const bf16x8*)((const char*)Xs + ((row * 256 + cb) ^ ((row & 7) << 4)));
                }
#pragma unroll
                for (int ni = 0; ni < 4; ++ni) {
                    int row = wn + ni * 16 + lr;
                    bfv[ni] = *(const bf16x8*)((const char*)Ws2 + ((row * 256 + cb) ^ ((row & 7) << 4)));
                }
#pragma unroll
                for (int mi = 0; mi < 2; ++mi)
#pragma unroll
                    for (int ni = 0; ni < 4; ++ni) {
                        if (g == 0)
                            aR[mi][ni] = __builtin_amdgcn_mfma_f32_16x16x32_bf16(af[mi], bfv[ni], aR[mi][ni], 0, 0, 0);
                        else if (g == 1)
                            aZ[mi][ni] = __builtin_amdgcn_mfma_f32_16x16x32_bf16(af[mi], bfv[ni], aZ[mi][ni], 0, 0, 0);
                        else if (pass == 0)
                            aI[mi][ni] = __builtin_amdgcn_mfma_f32_16x16x32_bf16(af[mi], bfv[ni], aI[mi][ni], 0, 0, 0);
                        else
                            aH[mi][ni] = __builtin_amdgcn_mfma_f32_16x16x32_bf16(af[mi], bfv[ni], aH[mi][ni], 0, 0, 0);
                    }
            }
        }
    }
    // epilogue: full GRU combine in-register
#pragma unroll
    for (int ni = 0; ni < 4; ++ni) {
        int col = wn + ni * 16 + lr;
        float br_ = bih[col] + bhh[col];
        float bz_ = bih[DD + col] + bhh[DD + col];
        float bin_ = bih[2 * DD + col], bhn_ = bhh[2 * DD + col];
#pragma unroll
        for (int mi = 0; mi < 2; ++mi)
#pragma unroll
            for (int rg = 0; rg < 4; ++rg) {
                int v = m0 + wm + mi * 16 + lk * 4 + rg;
                float rr = sigmoidf_(aR[mi][ni][rg] + br_);
                float zz = sigmoidf_(aZ[mi][ni][rg] + bz_);
                float nn = tanhf(aI[mi][ni][rg] + bin_ + rr * (aH[mi][ni][rg] + bhn_));
                float hold = h[(size_t)v * DD + col];
                float hnew = (1.f - zz) * nn + zz * hold;
                h[(size_t)v * DD + col] = hnew;
                hbf[(size_t)v * DD + col] = (unsigned short)f2b(hnew);
            }
    }
}

// ---------------- MFMA conv1(k=3): U1[b][pos][co] = relu(conv+b), unpooled, bf16 ----------------

template <int CIN>
__launch_bounds__(256, 2)
__global__ void k_conv1m(const unsigned short* __restrict__ hbf, const unsigned short* __restrict__ h0bf,
                         const unsigned short* __restrict__ w1p, const float* __restrict__ bias,
                         unsigned short* __restrict__ U1)
{
    __shared__ __align__(16) unsigned short As[128 * 64];
    __shared__ __align__(16) unsigned short Ws[128 * 64];
    int p0 = blockIdx.x * 128, b = blockIdx.y, n0 = blockIdx.z * 128;
    int tid = threadIdx.x;
    int lane = tid & 63, wv = tid >> 6;
    int wm = (wv >> 1) * 64, wn = (wv & 1) * 64;
    int lr = lane & 15, lk = lane >> 4;
    f32x4 acc[4][4];
#pragma unroll
    for (int i = 0; i < 4; ++i)
#pragma unroll
        for (int j = 0; j < 4; ++j) acc[i][j] = (f32x4){0.f, 0.f, 0.f, 0.f};

    int r = tid >> 1, halfc = tid & 1;
    unsigned boff = r * 128 + halfc * 64;
    unsigned sw = (r & 7) << 4;
#pragma unroll
    for (int k = 0; k < 3; ++k) {
        for (int c0 = 0; c0 < CIN; c0 += 64) {
            __syncthreads();
            {
                int row = p0 + k + r; if (row > NNODE - 1) row = NNODE - 1;
                int ci = c0 + halfc * 32;
                const unsigned short* srcp = (CIN == 128 || ci < 128)
                    ? hbf  + ((size_t)(b * NNODE + row)) * DD + ci
                    : h0bf + ((size_t)(b * NNODE + row)) * DD + (ci - 128);
                const uint4* sp = (const uint4*)srcp;
#pragma unroll
                for (int c = 0; c < 4; ++c)
                    *(uint4*)((char*)As + ((boff + c * 16) ^ sw)) = sp[c];
            }
            {
                const uint4* wp = (const uint4*)(w1p + ((size_t)k * CIN + n0 + r) * CIN + c0 + halfc * 32);
#pragma unroll
                for (int c = 0; c < 4; ++c)
                    *(uint4*)((char*)Ws + ((boff + c * 16) ^ sw)) = wp[c];
            }
            __syncthreads();
#pragma unroll
            for (int kc = 0; kc < 2; ++kc) {
                int cb = kc * 64 + lk * 16;
                bf16x8 af[4], bfv[4];
#pragma unroll
                for (int mi = 0; mi < 4; ++mi) {
                    int row = wm + mi * 16 + lr;
                    af[mi] = *(const bf16x8*)((const char*)As + ((row * 128 + cb) ^ ((row & 7) << 4)));
                }
#pragma unroll
                for (int ni = 0; ni < 4; ++ni) {
                    int row = wn + ni * 16 + lr;
                    bfv[ni] = *(const bf16x8*)((const char*)Ws + ((row * 128 + cb) ^ ((row & 7) << 4)));
                }
#pragma unroll
                for (int mi = 0; mi < 4; ++mi)
#pragma unroll
                    for (int ni = 0; ni < 4; ++ni)
                        acc[mi][ni] = __builtin_amdgcn_mfma_f32_16x16x32_bf16(af[mi], bfv[ni], acc[mi][ni], 0, 0, 0);
            }
        }
    }
#pragma unroll
    for (int ni = 0; ni < 4; ++ni) {
        int co = n0 + wn + ni * 16 + lr;
        float bs = bias[co];
#pragma unroll
        for (int mi = 0; mi < 4; ++mi)
#pragma unroll
            for (int rg = 0; rg < 4; ++rg) {
                int pos = p0 + wm + mi * 16 + lk * 4 + rg;
                if (pos < NNODE - 2) {
                    float v = fmaxf(0.f, acc[mi][ni][rg] + bs);
                    U1[((size_t)b * NNODE + pos) * CIN + co] = (unsigned short)f2b(v);
                }
            }
    }
}

// ---------------- MFMA conv2(k=1): A = pool3(U1) on the fly; epilogue pool2 ----------------

template <int CIN>
__launch_bounds__(256, 2)
__global__ void k_conv2m(const unsigned short* __restrict__ U1, const unsigned short* __restrict__ w2b,
                         const float* __restrict__ bias, float* __restrict__ Q)
{
    __shared__ __align__(16) unsigned short As[128 * 64];
    __shared__ __align__(16) unsigned short Ws[128 * 64];
    int m0 = blockIdx.x * 128, b = blockIdx.y, n0 = blockIdx.z * 128;
    int tid = threadIdx.x;
    int lane = tid & 63, wv = tid >> 6;
    int wm = (wv >> 1) * 64, wn = (wv & 1) * 64;
    int lr = lane & 15, lk = lane >> 4;
    f32x4 acc[4][4];
#pragma unroll
    for (int i = 0; i < 4; ++i)
#pragma unroll
        for (int j = 0; j < 4; ++j) acc[i][j] = (f32x4){0.f, 0.f, 0.f, 0.f};

    int r = tid >> 1, halfc = tid & 1;
    unsigned boff = r * 128 + halfc * 64;
    unsigned sw = (r & 7) << 4;
    for (int c0 = 0; c0 < CIN; c0 += 64) {
        __syncthreads();
        {
            int pr = 2 * (m0 + r);
            int r0 = pr, r1 = pr + 1, r2v = pr + 2;
            if (r2v > NNODE - 1) r2v = NNODE - 1;
            if (r1 > NNODE - 1) r1 = NNODE - 1;
            int ci = c0 + halfc * 32;
            const unsigned short* bp = U1 + (size_t)b * NNODE * CIN + ci;
            const uint4* p0q = (const uint4*)(bp + (size_t)r0 * CIN);
            const uint4* p1q = (const uint4*)(bp + (size_t)r1 * CIN);
            const uint4* p2q = (const uint4*)(bp + (size_t)r2v * CIN);
#pragma unroll
            for (int c = 0; c < 4; ++c) {
                uint4 mm = bmax4(bmax4(p0q[c], p1q[c]), p2q[c]);
                *(uint4*)((char*)As + ((boff + c * 16) ^ sw)) = mm;
            }
        }
        {
            const uint4* wp = (const uint4*)(w2b + (size_t)(n0 + r) * CIN + c0 + halfc * 32);
#pragma unroll
            for (int c = 0; c < 4; ++c)
                *(uint4*)((char*)Ws + ((boff + c * 16) ^ sw)) = wp[c];
        }
        __syncthreads();
#pragma unroll
        for (int kc = 0; kc < 2; ++kc) {
            int cb = kc * 64 + lk * 16;
            bf16x8 af[4], bfv[4];
#pragma unroll
            for (int mi = 0; mi < 4; ++mi) {
                int row = wm + mi * 16 + lr;
                af[mi] = *(const bf16x8*)((const char*)As + ((row * 128 + cb) ^ ((row & 7) << 4)));
            }
#pragma unroll
            for (int ni = 0; ni < 4; ++ni) {
                int row = wn + ni * 16 + lr;
                bfv[ni] = *(const bf16x8*)((const char*)Ws + ((row * 128 + cb) ^ ((row & 7) << 4)));
            }
#pragma unroll
            for (int mi = 0; mi < 4; ++mi)
#pragma unroll
                for (int ni = 0; ni < 4; ++ni)
                    acc[mi][ni] = __builtin_amdgcn_mfma_f32_16x16x32_bf16(af[mi], bfv[ni], acc[mi][ni], 0, 0, 0);
        }
    }
#pragma unroll
    for (int ni = 0; ni < 4; ++ni) {
        int co = n0 + wn + ni * 16 + lr;
        float bs = bias[co];
#pragma unroll
        for (int mi = 0; mi < 4; ++mi) {
            int l0 = m0 + wm + mi * 16 + lk * 4;
            float v0 = fmaxf(0.f, acc[mi][ni][0] + bs);
            float v1 = fmaxf(0.f, acc[mi][ni][1] + bs);
            float v2 = fmaxf(0.f, acc[mi][ni][2] + bs);
            float v3 = fmaxf(0.f, acc[mi][ni][3] + bs);
            int jq = l0 >> 1;
            if (jq < 255)     Q[((size_t)b * 255 + jq) * CIN + co]     = fmaxf(v0, v1);
            if (jq + 1 < 255) Q[((size_t)b * 255 + jq + 1) * CIN + co] = fmaxf(v2, v3);
        }
    }
}

// ---------------- final reduction ----------------

__launch_bounds__(256)
__global__ void k_final(const float* __restrict__ QY, const float* __restrict__ QZ,
                        const float* __restrict__ wy, const float* __restrict__ by,
                        const float* __restrict__ wz, const float* __restrict__ bz,
                        float* __restrict__ out)
{
    int b = blockIdx.x, tid = threadIdx.x;
    float p = 0.f;
    if (tid < 255) {
        const float* qy = QY + ((size_t)(b * 255 + tid)) * 128;
        const float* qz = QZ + ((size_t)(b * 255 + tid)) * 256;
        float dy = 0.f, dz = 0.f;
        for (int c = 0; c < 128; c += 4) {
            float4 q = ld4(qy + c), wv = ld4(wy + c);
            dy += q.x * wv.x + q.y * wv.y + q.z * wv.z + q.w * wv.w;
        }
        for (int c = 0; c < 256; c += 4) {
            float4 q = ld4(qz + c), wv = ld4(wz + c);
            dz += q.x * wv.x + q.y * wv.y + q.z * wv.z + q.w * wv.w;
        }
        p = (dy + by[0]) * (dz + bz[0]);
    }
    __shared__ float red[4];
    for (int off = 32; off > 0; off >>= 1) p += __shfl_down(p, off);
    if ((tid & 63) == 0) red[tid >> 6] = p;
    __syncthreads();
    if (tid == 0) {
        float s = red[0] + red[1] + red[2] + red[3];
        out[b] = 1.f / (1.f + expf(-s / 255.f));
    }
}

// ---------------- launch ----------------

extern "C" void kernel_launch(void* const* d_in, const int* in_sizes, int n_in,
                              void* d_out, int out_size, void* d_ws, size_t ws_size,
                              hipStream_t stream)
{
    const float* h_in = (const float*)d_in[0];
    const int* src = (const int*)d_in[1];
    const int* dst = (const int*)d_in[2];
    const int* et  = (const int*)d_in[3];
    const float* Wmsg = (const float*)d_in[4];
    const float* bmsg = (const float*)d_in[5];
    const float* wih = (const float*)d_in[6];
    const float* whh = (const float*)d_in[7];
    const float* bih = (const float*)d_in[8];
    const float* bhh = (const float*)d_in[9];
    const float* c1w = (const float*)d_in[10];
    const float* c1b = (const float*)d_in[11];
    const float* c2w = (const float*)d_in[12];
    const float* c2b = (const float*)d_in[13];
    const float* z1w = (const float*)d_in[14];
    const float* z1b = (const float*)d_in[15];
    const float* z2w = (const float*)d_in[16];
    const float* z2b = (const float*)d_in[17];
    const float* wy  = (const float*)d_in[18];
    const float* by  = (const float*)d_in[19];
    const float* wz  = (const float*)d_in[20];
    const float* bz  = (const float*)d_in[21];
    float* out = (float*)d_out;

    if (ws_size < WS_NEED) return;   // loud failure: output stays poisoned

    char* ws = (char*)d_ws;
    float* hcur = (float*)(ws + OFF_HCUR);
    unsigned short* hbf  = (unsigned short*)(ws + OFF_HBF);
    int*   cnt  = (int*)(ws + OFF_CNT);
    int*   doff = (int*)(ws + OFF_DOFF);
    int*   dblk = (int*)(ws + OFF_DBLK);
    int*   hb   = (int*)(ws + OFF_HB);
    int*   ssrc = (int*)(ws + OFF_SSRC);
    int*   sdst = (int*)(ws + OFF_SDST);
    int*   sq   = (int*)(ws + OFF_SQ);
    int*   dcur = (int*)(ws + OFF_DCUR);
    int*   deg  = (int*)(ws + OFF_DEG);
    unsigned short* wmb  = (unsigned short*)(ws + OFF_WMB);
    unsigned short* wihb = (unsigned short*)(ws + OFF_WIHB);
    unsigned short* whhb = (unsigned short*)(ws + OFF_WHHB);
    unsigned short* w1py = (unsigned short*)(ws + OFF_W1PY);
    unsigned short* w1pz = (unsigned short*)(ws + OFF_W1PZ);
    unsigned short* w2yb = (unsigned short*)(ws + OFF_W2YB);
    unsigned short* w2zb = (unsigned short*)(ws + OFF_W2ZB);
    unsigned short* abf  = (unsigned short*)(ws + OFF_ABF);
    unsigned short* h0bf = (unsigned short*)(ws + OFF_H0BF);
    unsigned short* mbuf = (unsigned short*)(ws + OFF_M);
    unsigned short* U1Y  = (unsigned short*)(ws + OFF_U1Y);
    unsigned short* U1Z  = (unsigned short*)(ws + OFF_U1Z);
    float* QY   = (float*)(ws + OFF_QY);
    float* QZ   = (float*)(ws + OFF_QZ);

    k_prep<<<PREP_BLOCKS, 256, 0, stream>>>(h_in, hcur, hbf, h0bf, Wmsg, wmb, wih, wihb, whh, whhb,
                                            c2w, w2yb, z2w, w2zb, c1w, w1py, z1w, w1pz,
                                            cnt, hb, ssrc, sdst);

    k_hist<<<256, 256, 0, stream>>>(et, dst, hb, cnt);
    k_degA<<<128, 256, 0, stream>>>(cnt, deg, doff, dblk);
    k_scan2<<<1, 128, 0, stream>>>(hb, dblk);
    k_degB<<<128, 256, 0, stream>>>(doff, dcur, dblk);
    k_scatter<<<256, 256, 0, stream>>>(src, dst, et, hb, dcur, ssrc, sdst, sq);

    for (int s = 0; s < NSTEPS; ++s) {
        k_msg<<<NTILES_F, 256, 0, stream>>>(ssrc, sdst, sq, hb, hbf, wmb, mbuf);
        k_agg<<<BN / 4, 256, 0, stream>>>(mbuf, deg, doff, cnt, bmsg, abf);
        k_gru<<<BN / 128, 512, 0, stream>>>(abf, hcur, hbf, wihb, whhb, bih, bhh);
    }

    k_conv1m<128><<<dim3(8, 32, 1), 256, 0, stream>>>(hbf, h0bf, w1py, c1b, U1Y);
    k_conv2m<128><<<dim3(4, 32, 1), 256, 0, stream>>>(U1Y, w2yb, c2b, QY);
    k_conv1m<256><<<dim3(8, 32, 2), 256, 0, stream>>>(hbf, h0bf, w1pz, z1b, U1Z);
    k_conv2m<256><<<dim3(4, 32, 2), 256, 0, stream>>>(U1Z, w2zb, z2b, QZ);
    k_final<<<32, 256, 0, stream>>>(QY, QZ, wy, by, wz, bz, out);
}